// Round 2
// baseline (10.347 us; speedup 1.0000x reference)
//
#include <hip/hip_runtime.h>

// P1 function-space evaluation on a regular 17x17 grid mesh over [0,1]^2.
// Direct cell location replaces the reference's 512-triangle scan.
// Vertex (i,j) -> weight index i*17+j, coord (i/16, j/16).
// Cell split: lower tri (v00,v10,v11) covers fy<=fx; upper (v00,v11,v01)
// covers fy>=fx. P1 interp is continuous so the diagonal tie is value-neutral.
//
// Reference boundary semantics: in_bb is STRICT and the 1e-10 bbox padding
// rounds away in float32 everywhere except at 0 — so points lying EXACTLY on
// an interior grid line (x*16 or y*16 an integer >= 1) are inside no
// triangle's bbox and the reference outputs 0 there. x*16 is exact in f32,
// so we detect this case exactly and emit 0.

#define NW 289  // 17*17 weights

__device__ __forceinline__ float eval_pt(float x, float y, const float* __restrict__ ws) {
    float gx = x * 16.0f;
    float gy = y * 16.0f;
    int i0 = (int)gx;
    int j0 = (int)gy;
    bool boundary = ((float)i0 == gx && i0 >= 1) || ((float)j0 == gy && j0 >= 1);
    int i = min(i0, 15);
    int j = min(j0, 15);
    float fx = gx - (float)i;
    float fy = gy - (float)j;
    const float* wb = &ws[i * 17 + j];
    float w00 = wb[0];
    float w01 = wb[1];
    float w10 = wb[17];
    float w11 = wb[18];
    bool up = fy > fx;
    float s  = up ? fx      : fx - fy;
    float tt = up ? fy - fx : fy;
    float c1 = up ? w11     : w10;
    float c2 = up ? w01     : w11;
    float val = (1.0f - s - tt) * w00 + s * c1 + tt * c2;
    return boundary ? 0.0f : val;
}

__global__ __launch_bounds__(256) void p1_eval_kernel(
    const float4* __restrict__ x4,   // 2 points per float4
    const float*  __restrict__ w,    // 289 vertex weights
    float2*       __restrict__ out2, // 2 outputs per float2
    int n4)
{
    __shared__ float ws[NW];
    for (int k = threadIdx.x; k < NW; k += 256) ws[k] = w[k];
    __syncthreads();

    int gid = blockIdx.x * 256 + threadIdx.x;
    if (gid >= n4) return;

    float4 v = x4[gid];
    float2 r;
    r.x = eval_pt(v.x, v.y, ws);
    r.y = eval_pt(v.z, v.w, ws);
    out2[gid] = r;
}

extern "C" void kernel_launch(void* const* d_in, const int* in_sizes, int n_in,
                              void* d_out, int out_size, void* d_ws, size_t ws_size,
                              hipStream_t stream) {
    // inputs: x (8,262144,2) f32, weight (289,) f32, tri_A, Minv, bbox, dofs (unused)
    const float4* x4 = (const float4*)d_in[0];
    const float*  w  = (const float*)d_in[1];
    float2* out2 = (float2*)d_out;

    int n_floats = in_sizes[0];      // 8*262144*2 = 4,194,304
    int n4 = n_floats / 4;           // 1,048,576 float4s (2 points each)
    int blocks = (n4 + 255) / 256;   // 4096

    p1_eval_kernel<<<blocks, 256, 0, stream>>>(x4, w, out2, n4);
}